// Round 5
// baseline (180.228 us; speedup 1.0000x reference)
//
#include <hip/hip_runtime.h>

// QNStepTD: n-step TD loss.
//   target[b] = sum_{t<T} gamma^t*reward[t,b] + gamma^T*next_n_q[b,na[b]]*(1-done[b])
//   td[b]     = (q[b,a[b]] - target[b])^2 ; loss = mean(td*weight)
// d_out layout: [loss, td[0..B-1]]
//
// History:
//  R1/R2: divergent row gathers, ~60-74us.
//  R3: block-wide 512-row LDS tile, coalesced float4 staging -> 62us main.
//  R4: per-wave slices, 0 barriers, 2x occupancy -> 65us (null at 1.4TB/s plateau).
//  R5: fused last-block finalize -> 165us. Per-block __threadfence on gfx950
//      (cross-XCD L2 writeback) wrecked the memory path. REVERTED.
//  R7: NT loads on q/nq -> 41us, 2.2TB/s. FETCH unchanged at 84MB => nt didn't
//      change miss traffic, it stopped L1/L2 pollution (small arrays stay hot).
//      Fabric itself does 6.6TB/s (restore fills) -> not at the path ceiling.
//  R8: kill the remaining phase serialization: separate q/nq LDS tiles
//      (TILE=256, 1 sample/thread, 32KB total), ALL global loads issued up
//      front, ONE staging barrier, both gathers after. 5 blocks/CU.

#define TILE  256                     // samples per block (1 per thread)
#define BLOCK 256

typedef float v4f __attribute__((ext_vector_type(4)));

__global__ __launch_bounds__(BLOCK) void qnstep_td_main(
    const float* __restrict__ q,
    const float* __restrict__ nq,
    const int*   __restrict__ act,
    const int*   __restrict__ nact,
    const float* __restrict__ rew,
    const int*   __restrict__ done,
    const float* __restrict__ w,
    const float* __restrict__ gamma_p,
    float*       __restrict__ out,      // out[1..B] = td
    float*       __restrict__ partial,  // per-block sums (d_ws)
    int B, int T)
{
    // fast path assumes N==16 (row == 64B == 4 float4) and B % TILE == 0
    __shared__ float tq[TILE * 16];     // 16 KB
    __shared__ float tn[TILE * 16];     // 16 KB

    const int tid  = threadIdx.x;
    const long long base = (long long)blockIdx.x * TILE;   // first sample
    const long long b    = base + tid;                     // this thread's sample
    const float gamma = gamma_p[0];

    // ---- issue the bulk NT loads FIRST (max bytes in flight immediately) ----
    const v4f* q4 = (const v4f*)q  + base * 4;   // 256 rows * 4 float4
    const v4f* n4 = (const v4f*)nq + base * 4;
    v4f qr0 = __builtin_nontemporal_load(q4 + tid);
    v4f qr1 = __builtin_nontemporal_load(q4 + tid + BLOCK);
    v4f qr2 = __builtin_nontemporal_load(q4 + tid + 2 * BLOCK);
    v4f qr3 = __builtin_nontemporal_load(q4 + tid + 3 * BLOCK);
    v4f nr0 = __builtin_nontemporal_load(n4 + tid);
    v4f nr1 = __builtin_nontemporal_load(n4 + tid + BLOCK);
    v4f nr2 = __builtin_nontemporal_load(n4 + tid + 2 * BLOCK);
    v4f nr3 = __builtin_nontemporal_load(n4 + tid + 3 * BLOCK);

    // ---- per-sample scalars (cached: small arrays stay L2/L3-hot) ----
    const int   a  = act[b];
    const int   na = nact[b];
    const int   dn = done[b];
    const float wt = w[b];

    // ---- n-step return ----
    float tgt = 0.f, f = 1.0f;
    #pragma unroll 8
    for (int t = 0; t < T; ++t) {
        tgt += f * rew[(long long)t * B + b];
        f *= gamma;
    }
    // f == gamma^T

    // ---- write both tiles, ONE barrier, both gathers ----
    v4f* tq4 = (v4f*)tq;
    v4f* tn4 = (v4f*)tn;
    tq4[tid]             = qr0;
    tq4[tid + BLOCK]     = qr1;
    tq4[tid + 2 * BLOCK] = qr2;
    tq4[tid + 3 * BLOCK] = qr3;
    tn4[tid]             = nr0;
    tn4[tid + BLOCK]     = nr1;
    tn4[tid + 2 * BLOCK] = nr2;
    tn4[tid + 3 * BLOCK] = nr3;
    __syncthreads();

    const float qa  = tq[tid * 16 + a];    // bank = (a + 16*(tid&1)) % 32
    const float nqa = tn[tid * 16 + na];

    // ---- target, td, store (NT: td never re-read by GPU) ----
    tgt += f * nqa * (dn ? 0.f : 1.f);
    const float e  = qa - tgt;
    const float td = e * e;
    __builtin_nontemporal_store(td, out + 1 + b);

    float val = td * wt;

    // ---- block reduction -> partial[blk] ----
    #pragma unroll
    for (int off = 32; off > 0; off >>= 1)
        val += __shfl_down(val, off, 64);

    __shared__ float ssum[BLOCK / 64];
    const int wave = tid >> 6, lane = tid & 63;
    if (lane == 0) ssum[wave] = val;
    __syncthreads();
    if (tid == 0) {
        float s = 0.f;
        #pragma unroll
        for (int i = 0; i < BLOCK / 64; ++i) s += ssum[i];
        partial[blockIdx.x] = s;    // normal store: re-read by reduce kernel
    }
}

// generic fallback (any N, any B) — 1 sample/thread
__global__ __launch_bounds__(256) void qnstep_td_generic(
    const float* __restrict__ q, const float* __restrict__ nq,
    const int* __restrict__ act, const int* __restrict__ nact,
    const float* __restrict__ rew, const int* __restrict__ done,
    const float* __restrict__ w, const float* __restrict__ gamma_p,
    float* __restrict__ out, float* __restrict__ partial,
    int B, int N, int T)
{
    const int b = blockIdx.x * blockDim.x + threadIdx.x;
    const float gamma = gamma_p[0];
    float val = 0.0f;
    if (b < B) {
        float f = 1.0f, tgt = 0.0f;
        for (int t = 0; t < T; ++t) { tgt += f * rew[(long long)t * B + b]; f *= gamma; }
        const float nd = (done[b] != 0) ? 0.f : 1.f;
        tgt += f * nq[(long long)b * N + nact[b]] * nd;
        const float d = q[(long long)b * N + act[b]] - tgt;
        const float td = d * d;
        out[1 + b] = td;
        val = td * w[b];
    }
    #pragma unroll
    for (int off = 32; off > 0; off >>= 1) val += __shfl_down(val, off, 64);
    __shared__ float ssum[4];
    if ((threadIdx.x & 63) == 0) ssum[threadIdx.x >> 6] = val;
    __syncthreads();
    if (threadIdx.x == 0)
        partial[blockIdx.x] = ssum[0] + ssum[1] + ssum[2] + ssum[3];
}

__global__ __launch_bounds__(1024) void qnstep_td_reduce(
    const float* __restrict__ partial, float* __restrict__ out,
    int n, float invB)
{
    const int tid = threadIdx.x;
    float v = 0.0f;
    for (int i = tid; i < n; i += 1024) v += partial[i];

    #pragma unroll
    for (int off = 32; off > 0; off >>= 1)
        v += __shfl_down(v, off, 64);

    __shared__ float ssum[16];
    if ((tid & 63) == 0) ssum[tid >> 6] = v;
    __syncthreads();

    if (tid == 0) {
        float s = 0.0f;
        #pragma unroll
        for (int i = 0; i < 16; ++i) s += ssum[i];
        out[0] = s * invB;  // overwrites poison
    }
}

extern "C" void kernel_launch(void* const* d_in, const int* in_sizes, int n_in,
                              void* d_out, int out_size, void* d_ws, size_t ws_size,
                              hipStream_t stream) {
    const float* q     = (const float*)d_in[0];
    const float* nq    = (const float*)d_in[1];
    const int*   act   = (const int*)d_in[2];
    const int*   nact  = (const int*)d_in[3];
    const float* rew   = (const float*)d_in[4];
    const int*   done  = (const int*)d_in[5];
    const float* w     = (const float*)d_in[6];
    const float* gamma = (const float*)d_in[7];

    const int B = in_sizes[2];            // action is (B,)
    const int N = in_sizes[0] / B;        // q is (B, N)
    const int T = in_sizes[4] / B;        // reward is (T, B)

    float* out     = (float*)d_out;
    float* partial = (float*)d_ws;

    if (N == 16 && (B % TILE) == 0) {
        const int grid = B / TILE;        // 4096 for B=1M
        qnstep_td_main<<<grid, BLOCK, 0, stream>>>(
            q, nq, act, nact, rew, done, w, gamma, out, partial, B, T);
        qnstep_td_reduce<<<1, 1024, 0, stream>>>(partial, out, grid, 1.0f / (float)B);
    } else {
        const int grid = (B + 255) / 256;
        qnstep_td_generic<<<grid, 256, 0, stream>>>(
            q, nq, act, nact, rew, done, w, gamma, out, partial, B, N, T);
        qnstep_td_reduce<<<1, 1024, 0, stream>>>(partial, out, grid, 1.0f / (float)B);
    }
}

// Round 7
// 175.227 us; speedup vs baseline: 1.0285x; 1.0285x over previous
//
#include <hip/hip_runtime.h>

// QNStepTD: n-step TD loss.
//   target[b] = sum_{t<T} gamma^t*reward[t,b] + gamma^T*next_n_q[b,na[b]]*(1-done[b])
//   td[b]     = (q[b,a[b]] - target[b])^2 ; loss = mean(td*weight)
// d_out layout: [loss, td[0..B-1]]
//
// History:
//  R1/R2: divergent cached gathers, ~60-74us @1.4TB/s plateau.
//  R3: block-wide LDS tiles, coalesced staging -> 62us (same plateau).
//  R4: per-wave slices, 0 barriers, 2x occupancy -> 65us. NULL.
//  R5: fused last-block finalize -> 165us. Per-block __threadfence on gfx950
//      = cross-XCD L2 writeback storm. REVERTED; two dispatches are cheap.
//  R7: NT loads on q/nq -> 41us @2.2TB/s. FETCH unchanged 84MB: nt stopped
//      L1/L2 pollution (small arrays stay hot), didn't change line traffic.
//  R8: one-barrier dual-tile, all loads up front -> 42us. NULL.
//  R9: NT divergent 4B gathers (demanded bytes 164->44MB) -> CORRECTNESS FAIL
//      (post-timing td divergence on a few samples). Suspect: nt-flagged
//      scalar loads racing the harness restore path (stale-line window that
//      contiguous dwordx4 NT staging never hit). DO NOT use nt on gathers.
//  Model (fits all rounds): per-CU in-flight line cap. ~2.6M demanded 64B
//      lines / 256 CU / 41us = ~0.1 lines/cy/CU ~= ~60 outstanding lines at
//      ~600cy avg latency (half MALL-hit, half HBM). Schedule/occupancy
//      changes null (R4/R8); gather wouldn't reduce LINES, only bytes.
//  R10: restore R7 verbatim (best passing: main 41.2us, total 176.4us).

#define TILE_ROWS 512                 // samples per block (2 per thread)
#define BLOCK     256

typedef float v4f __attribute__((ext_vector_type(4)));

__global__ __launch_bounds__(BLOCK) void qnstep_td_main(
    const float* __restrict__ q,
    const float* __restrict__ nq,
    const int*   __restrict__ act,
    const int*   __restrict__ nact,
    const float* __restrict__ rew,
    const int*   __restrict__ done,
    const float* __restrict__ w,
    const float* __restrict__ gamma_p,
    float*       __restrict__ out,      // out[1..B] = td
    float*       __restrict__ partial,  // per-block sums (d_ws)
    int B, int T)
{
    // fast path assumes N==16 (row == 64B == 4 float4) and B % TILE_ROWS == 0
    __shared__ float tile[TILE_ROWS * 16];          // 32 KB

    const int tid  = threadIdx.x;
    const long long base = (long long)blockIdx.x * TILE_ROWS;  // first sample
    const float gamma = gamma_p[0];

    // ---- per-sample scalars, coalesced 8B loads (2 samples/thread) ----
    // Normal (cached) loads: small arrays stay L2/L3-hot since the bulk
    // q/nq streams are NT and don't allocate.
    const long long g = base / 2 + tid;             // index into *2-vectors
    const int2   a2  = ((const int2*)act)[g];
    const int2   na2 = ((const int2*)nact)[g];
    const int2   d2  = ((const int2*)done)[g];
    const float2 w2  = ((const float2*)w)[g];

    // ---- n-step return ----
    float t0 = 0.f, t1 = 0.f, f = 1.0f;
    #pragma unroll 8
    for (int t = 0; t < T; ++t) {
        const float2 r2 = ((const float2*)(rew + (long long)t * B))[g];
        t0 += f * r2.x; t1 += f * r2.y;
        f *= gamma;
    }

    const int s0 = tid * 2, s1 = tid * 2 + 1;       // local sample ids

    // ---- stage q tile: 512 rows * 64B = 2048 float4, coalesced, NT ----
    v4f* t4 = (v4f*)tile;
    {
        const v4f* q4 = (const v4f*)q + base * 4;
        #pragma unroll
        for (int j = 0; j < 8; ++j)
            t4[tid + j * BLOCK] = __builtin_nontemporal_load(q4 + tid + j * BLOCK);
    }
    __syncthreads();
    const float qa0 = tile[s0 * 16 + a2.x];
    const float qa1 = tile[s1 * 16 + a2.y];
    __syncthreads();

    // ---- stage nq tile (reuse buffer), NT ----
    {
        const v4f* nq4 = (const v4f*)nq + base * 4;
        #pragma unroll
        for (int j = 0; j < 8; ++j)
            t4[tid + j * BLOCK] = __builtin_nontemporal_load(nq4 + tid + j * BLOCK);
    }
    __syncthreads();
    const float nqa0 = tile[s0 * 16 + na2.x];
    const float nqa1 = tile[s1 * 16 + na2.y];

    // ---- targets, td, store (NT: td never re-read by GPU) ----
    t0 += f * nqa0 * (d2.x ? 0.f : 1.f);
    t1 += f * nqa1 * (d2.y ? 0.f : 1.f);
    const float e0 = qa0 - t0, e1 = qa1 - t1;
    const float td0 = e0 * e0, td1 = e1 * e1;

    __builtin_nontemporal_store(td0, out + 1 + base + s0);
    __builtin_nontemporal_store(td1, out + 1 + base + s1);

    float val = td0 * w2.x + td1 * w2.y;

    // ---- block reduction -> partial[blk] ----
    #pragma unroll
    for (int off = 32; off > 0; off >>= 1)
        val += __shfl_down(val, off, 64);

    __shared__ float ssum[BLOCK / 64];
    const int wave = tid >> 6, lane = tid & 63;
    if (lane == 0) ssum[wave] = val;
    __syncthreads();
    if (tid == 0) {
        float s = 0.f;
        #pragma unroll
        for (int i = 0; i < BLOCK / 64; ++i) s += ssum[i];
        partial[blockIdx.x] = s;    // normal store: re-read by reduce kernel
    }
}

// generic fallback (any N, any B) — 1 sample/thread
__global__ __launch_bounds__(256) void qnstep_td_generic(
    const float* __restrict__ q, const float* __restrict__ nq,
    const int* __restrict__ act, const int* __restrict__ nact,
    const float* __restrict__ rew, const int* __restrict__ done,
    const float* __restrict__ w, const float* __restrict__ gamma_p,
    float* __restrict__ out, float* __restrict__ partial,
    int B, int N, int T)
{
    const int b = blockIdx.x * blockDim.x + threadIdx.x;
    const float gamma = gamma_p[0];
    float val = 0.0f;
    if (b < B) {
        float f = 1.0f, tgt = 0.0f;
        for (int t = 0; t < T; ++t) { tgt += f * rew[(long long)t * B + b]; f *= gamma; }
        const float nd = (done[b] != 0) ? 0.f : 1.f;
        tgt += f * nq[(long long)b * N + nact[b]] * nd;
        const float d = q[(long long)b * N + act[b]] - tgt;
        const float td = d * d;
        out[1 + b] = td;
        val = td * w[b];
    }
    #pragma unroll
    for (int off = 32; off > 0; off >>= 1) val += __shfl_down(val, off, 64);
    __shared__ float ssum[4];
    if ((threadIdx.x & 63) == 0) ssum[threadIdx.x >> 6] = val;
    __syncthreads();
    if (threadIdx.x == 0)
        partial[blockIdx.x] = ssum[0] + ssum[1] + ssum[2] + ssum[3];
}

__global__ __launch_bounds__(1024) void qnstep_td_reduce(
    const float* __restrict__ partial, float* __restrict__ out,
    int n, float invB)
{
    const int tid = threadIdx.x;
    float v = 0.0f;
    for (int i = tid; i < n; i += 1024) v += partial[i];

    #pragma unroll
    for (int off = 32; off > 0; off >>= 1)
        v += __shfl_down(v, off, 64);

    __shared__ float ssum[16];
    if ((tid & 63) == 0) ssum[tid >> 6] = v;
    __syncthreads();

    if (tid == 0) {
        float s = 0.0f;
        #pragma unroll
        for (int i = 0; i < 16; ++i) s += ssum[i];
        out[0] = s * invB;  // overwrites poison
    }
}

extern "C" void kernel_launch(void* const* d_in, const int* in_sizes, int n_in,
                              void* d_out, int out_size, void* d_ws, size_t ws_size,
                              hipStream_t stream) {
    const float* q     = (const float*)d_in[0];
    const float* nq    = (const float*)d_in[1];
    const int*   act   = (const int*)d_in[2];
    const int*   nact  = (const int*)d_in[3];
    const float* rew   = (const float*)d_in[4];
    const int*   done  = (const int*)d_in[5];
    const float* w     = (const float*)d_in[6];
    const float* gamma = (const float*)d_in[7];

    const int B = in_sizes[2];            // action is (B,)
    const int N = in_sizes[0] / B;        // q is (B, N)
    const int T = in_sizes[4] / B;        // reward is (T, B)

    float* out     = (float*)d_out;
    float* partial = (float*)d_ws;

    if (N == 16 && (B % TILE_ROWS) == 0) {
        const int grid = B / TILE_ROWS;   // 2048 for B=1M
        qnstep_td_main<<<grid, BLOCK, 0, stream>>>(
            q, nq, act, nact, rew, done, w, gamma, out, partial, B, T);
        qnstep_td_reduce<<<1, 1024, 0, stream>>>(partial, out, grid, 1.0f / (float)B);
    } else {
        const int grid = (B + 255) / 256;
        qnstep_td_generic<<<grid, 256, 0, stream>>>(
            q, nq, act, nact, rew, done, w, gamma, out, partial, B, N, T);
        qnstep_td_reduce<<<1, 1024, 0, stream>>>(partial, out, grid, 1.0f / (float)B);
    }
}